// Round 7
// baseline (646.645 us; speedup 1.0000x reference)
//
#include <hip/hip_runtime.h>
#include <math.h>

// Problem constants
#define N_ROWS 8192
#define M_COLS 2048
#define K_DIM  1024
#define NM     ((size_t)N_ROWS * M_COLS)

#define LAM       0.9090909090909091f         // GAMMA/(GAMMA+EPS)
#define LOG_M     7.624618986159398f          // log(2048)

#define SKB 512                                // sinkhorn blocks (2/CU co-resident)
#define RPB (N_ROWS / SKB)                     // 16 rows per block

typedef __bf16 bf16x8 __attribute__((ext_vector_type(8)));
typedef float  f32x4  __attribute__((ext_vector_type(4)));
typedef unsigned short u16x8 __attribute__((ext_vector_type(8)));
typedef _Float16 h8 __attribute__((ext_vector_type(8)));

// d_out memory map (64 MB):
//   row r (r<8192): bytes [r*8192, r*8192+4096)  = cost fp16 row r (2048 halves)
//                   bytes [r*8192+4096, +8192)   = "hole"
//   Xb bf16 row i (16 MB): hole i>>1, slot i&1
//   Yb bf16 row j ( 4 MB): base 32MB + hole (j>>1), slot j&1
// GEMM writes fp16 cost into even chunks while reading Xb/Yb from odd chunks.
// sk_flow (persistent, software grid barrier) reads cost once into registers,
// runs 3 sinkhorn iterations with cross-block traffic via device-scope atomics,
// then overwrites d_out with fp32 flow + dist. Block b's flow writes cover only
// its own rows (whose E is already in registers) -- no cross-block hazard.

static __device__ __forceinline__ size_t xb_off(int i) {
    return ((size_t)(i >> 1) << 13) + 4096 + ((size_t)(i & 1) << 11);
}
static __device__ __forceinline__ size_t yb_off(int j) {
    return ((size_t)1 << 25) + ((size_t)(j >> 1) << 13) + 4096 + ((size_t)(j & 1) << 11);
}

// ---------------------------------------------------------------------------
// fp32 pair -> packed bf16 (RNE)
// ---------------------------------------------------------------------------
static __device__ __forceinline__ unsigned pk_bf16(float a, float b) {
#if __has_builtin(__builtin_amdgcn_cvt_pk_bf16_f32)
    typedef __bf16 bf16x2 __attribute__((ext_vector_type(2)));
    bf16x2 r = __builtin_amdgcn_cvt_pk_bf16_f32(a, b);
    return __builtin_bit_cast(unsigned, r);
#else
    unsigned ua = __float_as_uint(a), ub = __float_as_uint(b);
    ua += 0x7FFFu + ((ua >> 16) & 1u);
    ub += 0x7FFFu + ((ub >> 16) & 1u);
    return (ua >> 16) | (ub & 0xFFFF0000u);
#endif
}

static __device__ __forceinline__ bf16x8 lds_frag(const unsigned short* p) {
    return __builtin_bit_cast(bf16x8, *(const u16x8*)p);
}

static __device__ __forceinline__ void gload16(const void* g, void* l) {
    __builtin_amdgcn_global_load_lds(
        (const __attribute__((address_space(1))) unsigned int*)g,
        (__attribute__((address_space(3))) unsigned int*)l, 16, 0, 0);
}

// ---------------------------------------------------------------------------
// rowinit: blocks 0..10239 = per-row stats + bf16 convert (X then Y rows);
//          block 10240     = params + zero sigma[3][2048] + cnt[3] + scalars.
// ---------------------------------------------------------------------------
__global__ __launch_bounds__(256) void rowinit(
    const float* __restrict__ X, const float* __restrict__ Y,
    unsigned char* __restrict__ outb,
    float* __restrict__ mx, float* __restrict__ sx, float* __restrict__ x2,
    float* __restrict__ my, float* __restrict__ sy, float* __restrict__ y2,
    const int* __restrict__ iters, const int* __restrict__ ipe,
    float* __restrict__ params, float* __restrict__ sigma,
    unsigned int* __restrict__ cnt,
    unsigned int* __restrict__ d2max, float* __restrict__ dist)
{
    const int b = blockIdx.x, tid = threadIdx.x;

    if (b == N_ROWS + M_COLS) {
        for (int k = tid; k < 3 * M_COLS; k += 256) sigma[k] = 0.0f;
        if (tid < 3) cnt[tid] = 0u;
        if (tid == 0) {
            float ramp = 10.0f * (float)ipe[0];
            float rho;
            if (ramp == 0.0f) {
                rho = 1.1f;
            } else {
                float cur = fminf(fmaxf((float)iters[0], 0.0f), ramp);
                float phase = 1.0f - cur / ramp;
                rho = expf(-5.0f * phase * phase) + 0.1f;
            }
            rho = fminf(rho, 1.0f);
            params[0] = rho;
            params[1] = logf(rho) - LOG_M;   // logb = log(rho/M)
            *d2max = 0u;
            *dist = 0.0f;
        }
        return;
    }

    const int lane = tid & 63, wave = tid >> 6;
    const bool isX = b < N_ROWS;
    const int row = isX ? b : b - N_ROWS;
    const float* src = isX ? (X + (size_t)row * K_DIM) : (Y + (size_t)row * K_DIM);
    const float4 v = ((const float4*)src)[tid];

    // bf16 convert into hole
    uint2 p; p.x = pk_bf16(v.x, v.y); p.y = pk_bf16(v.z, v.w);
    size_t off = isX ? xb_off(row) : yb_off(row);
    *(uint2*)(outb + off + (size_t)tid * 8) = p;

    float lmin = fminf(fminf(v.x, v.y), fminf(v.z, v.w));
    float lsum = v.x + v.y + v.z + v.w;
    float lsq  = v.x*v.x + v.y*v.y + v.z*v.z + v.w*v.w;

    #pragma unroll
    for (int o = 32; o > 0; o >>= 1) {
        lmin = fminf(lmin, __shfl_xor(lmin, o, 64));
        lsum += __shfl_xor(lsum, o, 64);
        lsq  += __shfl_xor(lsq, o, 64);
    }
    __shared__ float W0[4], W1[4], W2[4];
    if (lane == 0) { W0[wave] = lmin; W1[wave] = lsum; W2[wave] = lsq; }
    __syncthreads();
    if (tid == 0) {
        float m = fminf(fminf(W0[0], W0[1]), fminf(W0[2], W0[3]));
        float s = W1[0] + W1[1] + W1[2] + W1[3];
        float q = W2[0] + W2[1] + W2[2] + W2[3];
        float nn = q - 2.f * m * s + (float)K_DIM * m * m;   // ||a - min||^2
        if (isX) { mx[row] = m; sx[row] = s; x2[row] = nn; }
        else     { my[row] = m; sy[row] = s; y2[row] = nn; }
    }
}

// ---------------------------------------------------------------------------
// m97-style MFMA GEMM on pre-converted bf16 + cost epilogue (fp16 store).
// 128x128 tile, 4 waves (2x2 of 64x64), BK=32, global_load_lds width 16.
// (unchanged from round 4 -- proven 69.6 us)
// ---------------------------------------------------------------------------
__global__ __launch_bounds__(256) void gemm_cost_mfma(
    float* __restrict__ gbuf,
    const float* __restrict__ mx, const float* __restrict__ sx, const float* __restrict__ x2,
    const float* __restrict__ my, const float* __restrict__ sy, const float* __restrict__ y2,
    unsigned int* __restrict__ d2max)
{
    __shared__ unsigned short Ash[128 * 32];   // 8 KB, unpadded (global_load_lds)
    __shared__ unsigned short Bsh[128 * 32];   // 8 KB
    __shared__ float rmax[256];

    const unsigned char* outb = (const unsigned char*)gbuf;
    const int tid   = threadIdx.x;
    const int lane  = tid & 63;
    const int wave  = tid >> 6;
    const int wi    = wave >> 1;          // 0..1
    const int wj    = wave & 1;           // 0..1
    const int row16 = lane & 15;
    const int quad  = lane >> 4;          // 0..3
    const int i0 = blockIdx.y * 128, j0 = blockIdx.x * 128;

    const int chA = (lane & 3) * 16;       // byte chunk within 64 B row
    const unsigned char* pa[2];
    const unsigned char* pb[2];
    unsigned short* la[2];
    unsigned short* lb[2];
    #pragma unroll
    for (int p = 0; p < 2; ++p) {
        const int rt = (p * 4 + wave) * 16 + (lane >> 2);   // row in tile
        pa[p] = outb + xb_off(i0 + rt) + chA;
        pb[p] = outb + yb_off(j0 + rt) + chA;
        la[p] = &Ash[(p * 4 + wave) * 512];
        lb[p] = &Bsh[(p * 4 + wave) * 512];
    }

    f32x4 acc[4][4];
    #pragma unroll
    for (int u = 0; u < 4; ++u)
        #pragma unroll
        for (int v = 0; v < 4; ++v) acc[u][v] = (f32x4){0.f, 0.f, 0.f, 0.f};

    for (int kt = 0; kt < K_DIM; kt += 32) {
        gload16(pa[0], la[0]);
        gload16(pa[1], la[1]);
        gload16(pb[0], lb[0]);
        gload16(pb[1], lb[1]);
        pa[0] += 64; pa[1] += 64; pb[0] += 64; pb[1] += 64;
        __syncthreads();

        bf16x8 af[4], bf[4];
        #pragma unroll
        for (int t = 0; t < 4; ++t) {
            af[t] = lds_frag(&Ash[(wi * 64 + t * 16 + row16) * 32 + quad * 8]);
            bf[t] = lds_frag(&Bsh[(wj * 64 + t * 16 + row16) * 32 + quad * 8]);
        }
        #pragma unroll
        for (int ti = 0; ti < 4; ++ti)
            #pragma unroll
            for (int tj = 0; tj < 4; ++tj)
                acc[ti][tj] = __builtin_amdgcn_mfma_f32_16x16x32_bf16(
                    af[ti], bf[tj], acc[ti][tj], 0, 0, 0);
        __syncthreads();
    }

    // epilogue: C/D layout col=lane&15 (j), row=quad*4+reg (i); store fp16 cost
    _Float16* costh = (_Float16*)gbuf;
    float lmax = 0.0f;
    float myj[4], syj[4], yy[4];
    #pragma unroll
    for (int tj = 0; tj < 4; ++tj) {
        const int j = j0 + wj * 64 + tj * 16 + row16;
        myj[tj] = my[j]; syj[tj] = sy[j]; yy[tj] = y2[j];
    }
    #pragma unroll
    for (int ti = 0; ti < 4; ++ti) {
        #pragma unroll
        for (int reg = 0; reg < 4; ++reg) {
            const int i = i0 + wi * 64 + ti * 16 + quad * 4 + reg;
            const float mxi = mx[i], sxi = sx[i], xxi = x2[i];
            #pragma unroll
            for (int tj = 0; tj < 4; ++tj) {
                const int j = j0 + wj * 64 + tj * 16 + row16;
                float corr = mxi * syj[tj] + myj[tj] * sxi - (float)K_DIM * mxi * myj[tj];
                float d2 = xxi + yy[tj] - 2.0f * acc[ti][tj][reg] + 2.0f * corr;
                d2 = fmaxf(d2, 0.0f);
                lmax = fmaxf(lmax, d2);
                costh[(size_t)i * 4096 + j] = (_Float16)sqrtf(d2);
            }
        }
    }
    rmax[tid] = lmax;
    __syncthreads();
    for (int s = 128; s > 0; s >>= 1) {
        if (tid < s) rmax[tid] = fmaxf(rmax[tid], rmax[tid + s]);
        __syncthreads();
    }
    if (tid == 0) atomicMax(d2max, __float_as_uint(rmax[0]));
}

// ---------------------------------------------------------------------------
// Persistent Sinkhorn + flow + dist. PLAIN launch, 512 blocks x 256 threads.
// __launch_bounds__(256,2) guarantees 2 blocks/CU => all 512 co-resident.
// Software grid barrier: per-iteration arrival counter, device-scope atomics,
// one spinning thread per block, bounded spin (degrades to wrong answer, not
// a hang, if co-residency assumption ever breaks).
// ---------------------------------------------------------------------------
__global__ __launch_bounds__(256, 2) void sk_flow(
    float* __restrict__ outbuf, float* __restrict__ sigma,
    unsigned int* __restrict__ cnt, const float* __restrict__ params,
    const unsigned int* __restrict__ d2max, float* __restrict__ dist)
{
    const int tid  = threadIdx.x;
    const int lane = tid & 63;
    const int wave = tid >> 6;
    const int r0   = blockIdx.x * RPB;
    const float logb = params[1];
    const float invC10 = 10.0f * rsqrtf(__uint_as_float(*d2max));

    const _Float16* Eb = (const _Float16*)outbuf;

    // load fp16 cost rows -> E = exp(-10*cn) in registers (fp16)
    h8 E[RPB];
    #pragma unroll
    for (int r = 0; r < RPB; ++r) {
        h8 c = __builtin_bit_cast(h8, *(const uint4*)(Eb + (size_t)(r0 + r) * 4096 + 8 * tid));
        h8 e;
        #pragma unroll
        for (int k = 0; k < 8; ++k)
            e[k] = (_Float16)__expf(-(float)c[k] * invC10);
        E[r] = e;
    }

    __shared__ float R[RPB][4];
    __shared__ float W[RPB];

    float u8[8] = {1.f, 1.f, 1.f, 1.f, 1.f, 1.f, 1.f, 1.f};

    for (int it = 0; it < 3; ++it) {
        // pass A: t_r = sum_j E_rj * u_j  (block-local)
        float pr[RPB];
        #pragma unroll
        for (int r = 0; r < RPB; ++r) {
            float s = 0.0f;
            #pragma unroll
            for (int c = 0; c < 8; ++c) s += (float)E[r][c] * u8[c];
            pr[r] = s;
        }
        #pragma unroll
        for (int r = 0; r < RPB; ++r)
            #pragma unroll
            for (int off = 32; off > 0; off >>= 1)
                pr[r] += __shfl_xor(pr[r], off, 64);
        if (lane == 0)
            #pragma unroll
            for (int r = 0; r < RPB; ++r) R[r][wave] = pr[r];
        __syncthreads();
        if (tid < RPB) {
            float t = R[tid][0] + R[tid][1] + R[tid][2] + R[tid][3];
            W[tid] = __expf(-LAM * (logb + __logf(t)));
        }
        __syncthreads();

        // pass B: column partials -> device-scope atomic sigma accumulate
        float p[8] = {0.f, 0.f, 0.f, 0.f, 0.f, 0.f, 0.f, 0.f};
        #pragma unroll
        for (int r = 0; r < RPB; ++r) {
            const float wr = W[r];
            #pragma unroll
            for (int c = 0; c < 8; ++c) p[c] += (float)E[r][c] * wr;
        }
        float* sig = sigma + it * M_COLS + 8 * tid;
        #pragma unroll
        for (int c = 0; c < 8; ++c) atomicAdd(&sig[c], p[c]);

        // ---- software grid barrier (arrival counter it) ----
        __syncthreads();   // all this block's atomics drained (vmcnt0 pre-barrier)
        if (tid == 0) {
            __hip_atomic_fetch_add(&cnt[it], 1u, __ATOMIC_ACQ_REL,
                                   __HIP_MEMORY_SCOPE_AGENT);
            int spins = 0;
            while (__hip_atomic_load(&cnt[it], __ATOMIC_ACQUIRE,
                                     __HIP_MEMORY_SCOPE_AGENT) < SKB) {
                __builtin_amdgcn_s_sleep(8);
                if (++spins > (1 << 22)) break;   // safety valve: fail, don't hang
            }
        }
        __syncthreads();

        // u refresh from completed sigma (coherent atomic loads)
        #pragma unroll
        for (int c = 0; c < 8; ++c) {
            float s = __hip_atomic_load(&sig[c], __ATOMIC_RELAXED,
                                        __HIP_MEMORY_SCOPE_AGENT);
            u8[c] = (float)N_ROWS / s;
        }
    }

    // flow = E * w_r * u_j / (N*M), in-place fp32; dist += sum cn*flow.
    // Writes cover only this block's own rows (E already in registers).
    const float invNM = 1.0f / ((float)N_ROWS * (float)M_COLS);
    float local = 0.0f;
    #pragma unroll
    for (int r = 0; r < RPB; ++r) {
        const float wr = W[r];          // W holds 3rd-iteration w
        float fl[8];
        #pragma unroll
        for (int c = 0; c < 8; ++c) {
            float e = (float)E[r][c];
            float o = e * wr * u8[c] * invNM;
            fl[c] = o;
            float cn = -0.1f * __logf(fmaxf(e, 1e-7f));
            local += cn * o;
        }
        float4 o0 = {fl[0], fl[1], fl[2], fl[3]};
        float4 o1 = {fl[4], fl[5], fl[6], fl[7]};
        float* frow = outbuf + (size_t)(r0 + r) * M_COLS + 8 * tid;
        *(float4*)frow = o0;
        *(float4*)(frow + 4) = o1;
    }

    // block reduce dist -> one atomic per block
    #pragma unroll
    for (int off = 32; off > 0; off >>= 1)
        local += __shfl_xor(local, off, 64);
    __shared__ float red[4];
    if (lane == 0) red[wave] = local;
    __syncthreads();
    if (tid == 0) atomicAdd(dist, red[0] + red[1] + red[2] + red[3]);
}

// ---------------------------------------------------------------------------
extern "C" void kernel_launch(void* const* d_in, const int* in_sizes, int n_in,
                              void* d_out, int out_size, void* d_ws, size_t ws_size,
                              hipStream_t stream)
{
    const float* x     = (const float*)d_in[0];
    const float* y     = (const float*)d_in[1];
    const int*   iters = (const int*)d_in[2];
    const int*   ipe   = (const int*)d_in[3];
    float* out = (float*)d_out;
    float* ws  = (float*)d_ws;

    // ws layout (floats): ~150 KB
    float*        params = ws;                       // [0]=rho [1]=logb
    unsigned int* d2max  = (unsigned int*)(ws + 8);
    float* mx = ws + 16;                             // 8192
    float* sx = mx + N_ROWS;                         // 8192
    float* x2 = sx + N_ROWS;                         // 8192
    float* my = x2 + N_ROWS;                         // 2048
    float* sy = my + M_COLS;                         // 2048
    float* y2 = sy + M_COLS;                         // 2048
    float* sigma = y2 + M_COLS;                      // 3*2048
    unsigned int* cnt = (unsigned int*)(sigma + 3 * M_COLS);  // 3 counters

    float* dist = out + NM;

    rowinit<<<N_ROWS + M_COLS + 1, 256, 0, stream>>>(
        x, y, (unsigned char*)out, mx, sx, x2, my, sy, y2,
        iters, ipe, params, sigma, cnt, d2max, dist);
    gemm_cost_mfma<<<dim3(M_COLS / 128, N_ROWS / 128), 256, 0, stream>>>(
        out, mx, sx, x2, my, sy, y2, d2max);
    sk_flow<<<SKB, 256, 0, stream>>>(out, sigma, cnt, params, d2max, dist);
}